// Round 1
// baseline (1231.075 us; speedup 1.0000x reference)
//
#include <hip/hip_runtime.h>
#include <stdint.h>

#define NKEYS 65536
#define DIM   1024
#define BQ    4096
#define DXV   768
#define DYV   256
#define THRESH 0.01f

#define BM 128
#define BN 128
#define BK 64

typedef __attribute__((ext_vector_type(8))) short short8;
typedef __attribute__((ext_vector_type(4))) float f32x4;

__device__ __forceinline__ unsigned short f2bf(float f) {
  unsigned int u = __float_as_uint(f);
  u += 0x7fffu + ((u >> 16) & 1u);
  return (unsigned short)(u >> 16);
}

__device__ __forceinline__ void gl2lds16(const void* g, void* l) {
  __builtin_amdgcn_global_load_lds(
      (const __attribute__((address_space(1))) unsigned int*)g,
      (__attribute__((address_space(3))) unsigned int*)l, 16, 0, 0);
}

__device__ __forceinline__ unsigned int orderf(float f) {
  unsigned int u = __float_as_uint(f);
  return (u & 0x80000000u) ? ~u : (u | 0x80000000u);
}

// ---------------- prep: keys fp32 -> bf16, fused row norms ----------------
__global__ void prep_keys(const float* __restrict__ keys,
                          unsigned short* __restrict__ Kb,
                          float* __restrict__ knorm) {
  const int row = blockIdx.x;
  const int t = threadIdx.x;          // 256 threads, 4 float each
  const float4 v = ((const float4*)(keys + (size_t)row * DIM))[t];
  ushort4 o;
  o.x = f2bf(v.x); o.y = f2bf(v.y); o.z = f2bf(v.z); o.w = f2bf(v.w);
  *(ushort4*)(Kb + (size_t)row * DIM + t * 4) = o;
  float s = v.x * v.x + v.y * v.y + v.z * v.z + v.w * v.w;
  for (int m = 32; m; m >>= 1) s += __shfl_xor(s, m);
  __shared__ float red[4];
  const int lane = t & 63, wave = t >> 6;
  if (lane == 0) red[wave] = s;
  __syncthreads();
  if (t == 0) knorm[row] = red[0] + red[1] + red[2] + red[3];
}

// ---------------- prep: q = concat(X, Y) -> bf16 ----------------
__global__ void prep_q(const float* __restrict__ X, const float* __restrict__ Y,
                       unsigned short* __restrict__ Qb) {
  const int row = blockIdx.x;
  const int t = threadIdx.x;          // 256 threads
  float4 v;
  unsigned short* dst = Qb + (size_t)row * DIM;
  if (t < 192) { v = ((const float4*)(X + (size_t)row * DXV))[t]; dst += t * 4; }
  else         { v = ((const float4*)(Y + (size_t)row * DYV))[t - 192]; dst += DXV + (t - 192) * 4; }
  ushort4 o;
  o.x = f2bf(v.x); o.y = f2bf(v.y); o.z = f2bf(v.z); o.w = f2bf(v.w);
  *(ushort4*)dst = o;
}

// ---------------- main: bf16 MFMA GEMM + fused argmin ----------------
// scores m = knorm[n] - 2*dot(keys[n], q[b]); argmin_n per b, merged via
// packed u64 (ordered-float<<32 | n) atomicMin.
__global__ __launch_bounds__(256, 3) void gemm_argmin(
    const unsigned short* __restrict__ Kb,   // [NKEYS][DIM] bf16
    const unsigned short* __restrict__ Qb,   // [BQ][DIM] bf16
    const float* __restrict__ knorm,         // [NKEYS]
    unsigned long long* __restrict__ best) { // [BQ]
  __shared__ __align__(16) unsigned short As[BM * BK];  // q tile [m][k]
  __shared__ __align__(16) unsigned short Bs[BN * BK];  // keys tile [n][k]
  __shared__ unsigned long long cand[2][BM];

  const int bid = blockIdx.x;
  const int mtile = bid & 31;          // m-fastest: 32 blocks share a keys tile
  const int ntile = bid >> 5;
  const int tid = threadIdx.x;
  const int wave = tid >> 6;
  const int lane = tid & 63;
  const int wm = wave >> 1;
  const int wn = wave & 1;
  const int lr = lane & 15;
  const int quad = lane >> 4;

  // staging map: 16 chunks of 1KB; wave w owns chunks 4w..4w+3; lane adds l*16B
  const char* agl[4]; const char* bgl[4];
  void* aldst[4]; void* bldst[4];
#pragma unroll
  for (int c = 0; c < 4; ++c) {
    const int chunk = wave * 4 + c;
    const int off = chunk * 1024 + lane * 16;  // byte offset in 16KB tile
    const int r = off >> 7;                    // row (128B = 64 bf16 per row)
    const int kb = off & 127;                  // byte offset within row's K-slice
    agl[c] = (const char*)Qb + ((size_t)(mtile * BM + r) * DIM * 2 + kb);
    bgl[c] = (const char*)Kb + ((size_t)(ntile * BN + r) * DIM * 2 + kb);
    aldst[c] = (void*)((char*)As + chunk * 1024);
    bldst[c] = (void*)((char*)Bs + chunk * 1024);
  }

  f32x4 acc[4][4];
#pragma unroll
  for (int i = 0; i < 4; ++i)
#pragma unroll
    for (int j = 0; j < 4; ++j) acc[i][j] = (f32x4)0.0f;

  for (int kt = 0; kt < DIM / BK; ++kt) {
    const size_t ko = (size_t)kt * (BK * 2);
#pragma unroll
    for (int c = 0; c < 4; ++c) gl2lds16(agl[c] + ko, aldst[c]);
#pragma unroll
    for (int c = 0; c < 4; ++c) gl2lds16(bgl[c] + ko, bldst[c]);
    __syncthreads();
#pragma unroll
    for (int ks = 0; ks < 2; ++ks) {
      short8 af[4], bfv[4];
#pragma unroll
      for (int fm = 0; fm < 4; ++fm)
        af[fm] = *(const short8*)&As[(wm * 64 + fm * 16 + lr) * BK + ks * 32 + quad * 8];
#pragma unroll
      for (int fn = 0; fn < 4; ++fn)
        bfv[fn] = *(const short8*)&Bs[(wn * 64 + fn * 16 + lr) * BK + ks * 32 + quad * 8];
#pragma unroll
      for (int fm = 0; fm < 4; ++fm)
#pragma unroll
        for (int fn = 0; fn < 4; ++fn)
          acc[fm][fn] = __builtin_amdgcn_mfma_f32_16x16x32_bf16(
              af[fm], bfv[fn], acc[fm][fn], 0, 0, 0);
    }
    __syncthreads();
  }

  // ---- epilogue: per-row argmin over this block's 128-wide n range ----
  // C/D layout: n = lane&15 (per frag_n), m = quad*4 + reg (per frag_m)
  const int nbase = ntile * BN + wn * 64 + lr;
  float kn[4];
#pragma unroll
  for (int fn = 0; fn < 4; ++fn) kn[fn] = knorm[nbase + fn * 16];

#pragma unroll
  for (int fm = 0; fm < 4; ++fm) {
#pragma unroll
    for (int reg = 0; reg < 4; ++reg) {
      float bv = kn[0] - 2.0f * acc[fm][0][reg];
      int bn = nbase;
#pragma unroll
      for (int fn = 1; fn < 4; ++fn) {
        const float v = kn[fn] - 2.0f * acc[fm][fn][reg];
        if (v < bv) { bv = v; bn = nbase + fn * 16; }
      }
      unsigned long long p =
          ((unsigned long long)orderf(bv) << 32) | (unsigned int)bn;
#pragma unroll
      for (int mask = 1; mask <= 8; mask <<= 1) {
        const unsigned long long q = __shfl_xor(p, mask);
        p = q < p ? q : p;
      }
      if (lr == 0) cand[wn][wm * 64 + fm * 16 + quad * 4 + reg] = p;
    }
  }
  __syncthreads();
  if (tid < BM) {
    const unsigned long long a = cand[0][tid], b = cand[1][tid];
    const unsigned long long m = b < a ? b : a;
    atomicMin(&best[(size_t)mtile * BM + tid], m);
  }
}

// ---------------- finalize: exact fp32 d at winner, ball test, gather ----------------
__global__ void finalize(const unsigned long long* __restrict__ best,
                         const float* __restrict__ keys,
                         const float* __restrict__ values,
                         const int* __restrict__ pi,
                         const float* __restrict__ X,
                         const float* __restrict__ Y,
                         float* __restrict__ out) {
  const int b = blockIdx.x;
  const int t = threadIdx.x;  // 256
  const unsigned long long pk = best[b];
  const int n = (int)(unsigned int)(pk & 0xffffffffull);

  const float4 kv = ((const float4*)(keys + (size_t)n * DIM))[t];
  const float4 qv = (t < 192) ? ((const float4*)(X + (size_t)b * DXV))[t]
                              : ((const float4*)(Y + (size_t)b * DYV))[t - 192];
  const float dx = kv.x - qv.x, dy = kv.y - qv.y, dz = kv.z - qv.z, dw = kv.w - qv.w;
  float s = dx * dx + dy * dy + dz * dz + dw * dw;
  for (int m = 32; m; m >>= 1) s += __shfl_xor(s, m);
  __shared__ float red[4];
  __shared__ float flagS;
  const int lane = t & 63, wave = t >> 6;
  if (lane == 0) red[wave] = s;
  __syncthreads();
  if (t == 0)
    flagS = (red[0] + red[1] + red[2] + red[3] <= THRESH) ? 1.0f : 0.0f;
  __syncthreads();
  const float flag = flagS;
  const int row = pi[n];
  if (t < 192) {
    const float4 v = ((const float4*)(values + (size_t)row * DXV))[t];
    float4 o;
    o.x = v.x * flag; o.y = v.y * flag; o.z = v.z * flag; o.w = v.w * flag;
    ((float4*)(out + (size_t)b * DXV))[t] = o;
  }
}

extern "C" void kernel_launch(void* const* d_in, const int* in_sizes, int n_in,
                              void* d_out, int out_size, void* d_ws, size_t ws_size,
                              hipStream_t stream) {
  const float* keys   = (const float*)d_in[0];
  const float* values = (const float*)d_in[1];
  const int*   pi     = (const int*)d_in[2];
  const float* X      = (const float*)d_in[3];
  const float* Y      = (const float*)d_in[4];
  float* out = (float*)d_out;

  char* ws = (char*)d_ws;
  unsigned short* Kb = (unsigned short*)ws;                       // 128 MB
  unsigned short* Qb = (unsigned short*)(ws + (size_t)NKEYS * DIM * 2);  // 8 MB
  float* knorm = (float*)(ws + (size_t)NKEYS * DIM * 2 + (size_t)BQ * DIM * 2);
  unsigned long long* best =
      (unsigned long long*)(ws + (size_t)NKEYS * DIM * 2 + (size_t)BQ * DIM * 2 +
                            (size_t)NKEYS * 4);

  hipMemsetAsync(best, 0xFF, (size_t)BQ * 8, stream);
  prep_keys<<<NKEYS, 256, 0, stream>>>(keys, Kb, knorm);
  prep_q<<<BQ, 256, 0, stream>>>(X, Y, Qb);
  gemm_argmin<<<(NKEYS / BN) * (BQ / BM), 256, 0, stream>>>(Kb, Qb, knorm, best);
  finalize<<<BQ, 256, 0, stream>>>(best, keys, values, pi, X, Y, out);
}

// Round 2
// 1004.869 us; speedup vs baseline: 1.2251x; 1.2251x over previous
//
#include <hip/hip_runtime.h>
#include <stdint.h>

#define NKEYS 65536
#define DIM   1024
#define BQ    4096
#define DXV   768
#define DYV   256
#define THRESH 0.01f

#define BM 128
#define BN 128
#define BK 64

typedef __attribute__((ext_vector_type(8))) short short8;
typedef __attribute__((ext_vector_type(4))) float f32x4;

__device__ __forceinline__ unsigned short f2bf(float f) {
  unsigned int u = __float_as_uint(f);
  u += 0x7fffu + ((u >> 16) & 1u);
  return (unsigned short)(u >> 16);
}

__device__ __forceinline__ void gl2lds16(const void* g, void* l) {
  __builtin_amdgcn_global_load_lds(
      (const __attribute__((address_space(1))) unsigned int*)g,
      (__attribute__((address_space(3))) unsigned int*)l, 16, 0, 0);
}

__device__ __forceinline__ unsigned int orderf(float f) {
  unsigned int u = __float_as_uint(f);
  return (u & 0x80000000u) ? ~u : (u | 0x80000000u);
}

// ---------------- prep: keys fp32 -> bf16, fused row norms ----------------
__global__ void prep_keys(const float* __restrict__ keys,
                          unsigned short* __restrict__ Kb,
                          float* __restrict__ knorm) {
  const int row = blockIdx.x;
  const int t = threadIdx.x;          // 256 threads, 4 float each
  const float4 v = ((const float4*)(keys + (size_t)row * DIM))[t];
  ushort4 o;
  o.x = f2bf(v.x); o.y = f2bf(v.y); o.z = f2bf(v.z); o.w = f2bf(v.w);
  *(ushort4*)(Kb + (size_t)row * DIM + t * 4) = o;
  float s = v.x * v.x + v.y * v.y + v.z * v.z + v.w * v.w;
  for (int m = 32; m; m >>= 1) s += __shfl_xor(s, m);
  __shared__ float red[4];
  const int lane = t & 63, wave = t >> 6;
  if (lane == 0) red[wave] = s;
  __syncthreads();
  if (t == 0) knorm[row] = red[0] + red[1] + red[2] + red[3];
}

// ---------------- prep: q = concat(X, Y) -> bf16 ----------------
__global__ void prep_q(const float* __restrict__ X, const float* __restrict__ Y,
                       unsigned short* __restrict__ Qb) {
  const int row = blockIdx.x;
  const int t = threadIdx.x;          // 256 threads
  float4 v;
  unsigned short* dst = Qb + (size_t)row * DIM;
  if (t < 192) { v = ((const float4*)(X + (size_t)row * DXV))[t]; dst += t * 4; }
  else         { v = ((const float4*)(Y + (size_t)row * DYV))[t - 192]; dst += DXV + (t - 192) * 4; }
  ushort4 o;
  o.x = f2bf(v.x); o.y = f2bf(v.y); o.z = f2bf(v.z); o.w = f2bf(v.w);
  *(ushort4*)dst = o;
}

// ---------------- main: bf16 MFMA GEMM + fused argmin ----------------
// scores = knorm[n] - 2*dot(keys[n], q[b]); argmin_n per b, merged via
// packed u64 (ordered-float<<32 | n) atomicMin.
// LDS layout is XOR-swizzled: LDS[r][c16] holds global[r][c16 ^ (r&7)] where
// c16 is the 16-byte chunk index within the 128-byte row slice. Staging DMA
// stays linear in LDS (global_load_lds constraint); the permutation is done
// on the per-lane *source* address. Reads apply the same XOR -> 8 lanes per
// chunk position per wave64 ds_read_b128 = conflict-free (8-cycle floor).
__global__ __launch_bounds__(256, 4) void gemm_argmin(
    const unsigned short* __restrict__ Kb,   // [NKEYS][DIM] bf16
    const unsigned short* __restrict__ Qb,   // [BQ][DIM] bf16
    const float* __restrict__ knorm,         // [NKEYS]
    unsigned long long* __restrict__ best) { // [BQ]
  __shared__ __align__(16) unsigned short As[BM * BK];  // q tile [m][k]
  __shared__ __align__(16) unsigned short Bs[BN * BK];  // keys tile [n][k]
  __shared__ unsigned long long cand[2][BM];

  const int bid = blockIdx.x;
  const int mtile = bid & 31;          // m-fastest: 32 blocks share a keys tile
  const int ntile = bid >> 5;
  const int tid = threadIdx.x;
  const int wave = tid >> 6;
  const int lane = tid & 63;
  const int wm = wave >> 1;
  const int wn = wave & 1;
  const int lr = lane & 15;
  const int quad = lane >> 4;

  // staging map: 16 chunks of 1KB; wave w owns chunks 4w..4w+3; lane adds l*16B
  const char* agl[4]; const char* bgl[4];
  void* aldst[4]; void* bldst[4];
#pragma unroll
  for (int c = 0; c < 4; ++c) {
    const int chunk = wave * 4 + c;
    const int off = chunk * 1024 + lane * 16;  // byte offset in 16KB tile
    const int r = off >> 7;                    // row (128B = 64 bf16 per row)
    const int kb = (off & 127) ^ ((r & 7) * 16); // swizzled source byte col
    agl[c] = (const char*)Qb + ((size_t)(mtile * BM + r) * DIM * 2 + kb);
    bgl[c] = (const char*)Kb + ((size_t)(ntile * BN + r) * DIM * 2 + kb);
    aldst[c] = (void*)((char*)As + chunk * 1024);
    bldst[c] = (void*)((char*)Bs + chunk * 1024);
  }

  f32x4 acc[4][4];
#pragma unroll
  for (int i = 0; i < 4; ++i)
#pragma unroll
    for (int j = 0; j < 4; ++j) acc[i][j] = (f32x4)0.0f;

  const int swz = (lr & 7) * 16;  // read-side byte swizzle (row&7 == lr&7)
  const char* Ab = (const char*)As;
  const char* Bb = (const char*)Bs;

  for (int kt = 0; kt < DIM / BK; ++kt) {
    const size_t ko = (size_t)kt * (BK * 2);
#pragma unroll
    for (int c = 0; c < 4; ++c) gl2lds16(agl[c] + ko, aldst[c]);
#pragma unroll
    for (int c = 0; c < 4; ++c) gl2lds16(bgl[c] + ko, bldst[c]);
    __syncthreads();
#pragma unroll
    for (int ks = 0; ks < 2; ++ks) {
      const int col = (ks * 64 + quad * 16) ^ swz;  // swizzled byte col
      short8 af[4], bfv[4];
#pragma unroll
      for (int fm = 0; fm < 4; ++fm)
        af[fm] = *(const short8*)(Ab + (wm * 64 + fm * 16 + lr) * 128 + col);
#pragma unroll
      for (int fn = 0; fn < 4; ++fn)
        bfv[fn] = *(const short8*)(Bb + (wn * 64 + fn * 16 + lr) * 128 + col);
#pragma unroll
      for (int fm = 0; fm < 4; ++fm)
#pragma unroll
        for (int fn = 0; fn < 4; ++fn)
          acc[fm][fn] = __builtin_amdgcn_mfma_f32_16x16x32_bf16(
              af[fm], bfv[fn], acc[fm][fn], 0, 0, 0);
    }
    __syncthreads();
  }

  // ---- epilogue: per-row argmin over this block's 128-wide n range ----
  // C/D layout: n = lane&15 (per frag_n), m = quad*4 + reg (per frag_m)
  const int nbase = ntile * BN + wn * 64 + lr;
  float kn[4];
#pragma unroll
  for (int fn = 0; fn < 4; ++fn) kn[fn] = knorm[nbase + fn * 16];

#pragma unroll
  for (int fm = 0; fm < 4; ++fm) {
#pragma unroll
    for (int reg = 0; reg < 4; ++reg) {
      float bv = kn[0] - 2.0f * acc[fm][0][reg];
      int bn = nbase;
#pragma unroll
      for (int fn = 1; fn < 4; ++fn) {
        const float v = kn[fn] - 2.0f * acc[fm][fn][reg];
        if (v < bv) { bv = v; bn = nbase + fn * 16; }
      }
      unsigned long long p =
          ((unsigned long long)orderf(bv) << 32) | (unsigned int)bn;
#pragma unroll
      for (int mask = 1; mask <= 8; mask <<= 1) {
        const unsigned long long q = __shfl_xor(p, mask);
        p = q < p ? q : p;
      }
      if (lr == 0) cand[wn][wm * 64 + fm * 16 + quad * 4 + reg] = p;
    }
  }
  __syncthreads();
  if (tid < BM) {
    const unsigned long long a = cand[0][tid], b = cand[1][tid];
    const unsigned long long m = b < a ? b : a;
    atomicMin(&best[(size_t)mtile * BM + tid], m);
  }
}

// ---------------- finalize: exact fp32 d at winner, ball test, gather ----------------
__global__ void finalize(const unsigned long long* __restrict__ best,
                         const float* __restrict__ keys,
                         const float* __restrict__ values,
                         const int* __restrict__ pi,
                         const float* __restrict__ X,
                         const float* __restrict__ Y,
                         float* __restrict__ out) {
  const int b = blockIdx.x;
  const int t = threadIdx.x;  // 256
  const unsigned long long pk = best[b];
  const int n = (int)(unsigned int)(pk & 0xffffffffull);

  const float4 kv = ((const float4*)(keys + (size_t)n * DIM))[t];
  const float4 qv = (t < 192) ? ((const float4*)(X + (size_t)b * DXV))[t]
                              : ((const float4*)(Y + (size_t)b * DYV))[t - 192];
  const float dx = kv.x - qv.x, dy = kv.y - qv.y, dz = kv.z - qv.z, dw = kv.w - qv.w;
  float s = dx * dx + dy * dy + dz * dz + dw * dw;
  for (int m = 32; m; m >>= 1) s += __shfl_xor(s, m);
  __shared__ float red[4];
  __shared__ float flagS;
  const int lane = t & 63, wave = t >> 6;
  if (lane == 0) red[wave] = s;
  __syncthreads();
  if (t == 0)
    flagS = (red[0] + red[1] + red[2] + red[3] <= THRESH) ? 1.0f : 0.0f;
  __syncthreads();
  const float flag = flagS;
  const int row = pi[n];
  if (t < 192) {
    const float4 v = ((const float4*)(values + (size_t)row * DXV))[t];
    float4 o;
    o.x = v.x * flag; o.y = v.y * flag; o.z = v.z * flag; o.w = v.w * flag;
    ((float4*)(out + (size_t)b * DXV))[t] = o;
  }
}

extern "C" void kernel_launch(void* const* d_in, const int* in_sizes, int n_in,
                              void* d_out, int out_size, void* d_ws, size_t ws_size,
                              hipStream_t stream) {
  const float* keys   = (const float*)d_in[0];
  const float* values = (const float*)d_in[1];
  const int*   pi     = (const int*)d_in[2];
  const float* X      = (const float*)d_in[3];
  const float* Y      = (const float*)d_in[4];
  float* out = (float*)d_out;

  char* ws = (char*)d_ws;
  unsigned short* Kb = (unsigned short*)ws;                       // 128 MB
  unsigned short* Qb = (unsigned short*)(ws + (size_t)NKEYS * DIM * 2);  // 8 MB
  float* knorm = (float*)(ws + (size_t)NKEYS * DIM * 2 + (size_t)BQ * DIM * 2);
  unsigned long long* best =
      (unsigned long long*)(ws + (size_t)NKEYS * DIM * 2 + (size_t)BQ * DIM * 2 +
                            (size_t)NKEYS * 4);

  hipMemsetAsync(best, 0xFF, (size_t)BQ * 8, stream);
  prep_keys<<<NKEYS, 256, 0, stream>>>(keys, Kb, knorm);
  prep_q<<<BQ, 256, 0, stream>>>(X, Y, Qb);
  gemm_argmin<<<(NKEYS / BN) * (BQ / BM), 256, 0, stream>>>(Kb, Qb, knorm, best);
  finalize<<<BQ, 256, 0, stream>>>(best, keys, values, pi, X, Y, out);
}